// Round 4
// baseline (2420.816 us; speedup 1.0000x reference)
//
#include <hip/hip_runtime.h>
#include <hip/hip_bf16.h>
#include <math.h>

namespace {

constexpr int cE  = 512;    // embed dim
constexpr int cH  = 512;    // total hidden (2 dirs)
constexpr int cT  = 76;     // tags
constexpr int cB  = 256;    // batch
constexpr int cS  = 128;    // seq len
constexpr int cHD = 256;    // per-dir hidden
constexpr int cNG = 1024;   // 4*HD gate width
constexpr int cM  = cS * cB; // 32768 rows of (S,B) flattened
constexpr int cV  = 30000;  // vocab

typedef __attribute__((ext_vector_type(8))) short bf16x8;
typedef __attribute__((ext_vector_type(4))) float f32x4;

typedef const __attribute__((address_space(1))) unsigned int* gas_ptr;
typedef __attribute__((address_space(3))) unsigned int* las_ptr;

__device__ __forceinline__ float fsig(float x) { return 1.0f / (1.0f + __expf(-x)); }
__device__ __forceinline__ float ftanh_(float x) {
  float e = __expf(2.0f * fabsf(x));
  float t = 1.0f - 2.0f / (e + 1.0f);
  return copysignf(t, x);
}
__device__ __forceinline__ unsigned short f2bf(float f) {
  __hip_bfloat16 h = __float2bfloat16(f);
  return *reinterpret_cast<unsigned short*>(&h);
}
__device__ __forceinline__ float bf2f(unsigned short u) {
  unsigned int v = ((unsigned int)u) << 16;
  return *reinterpret_cast<float*>(&v);
}
__device__ __forceinline__ void gload_lds16(const void* g, void* l) {
  __builtin_amdgcn_global_load_lds((gas_ptr)g, (las_ptr)l, 16, 0, 0);
}

// ---------------------------------------------------------------------------
// Prep: bf16-convert embed table, W_ih (both), W_hh (both), h0; zero barriers.
// All vectorized float4 -> ushort4 grid-stride.
// ---------------------------------------------------------------------------
__global__ __launch_bounds__(256) void k_prep(
    const float* __restrict__ embed,
    const float* __restrict__ Wihf, const float* __restrict__ Wihb,
    const float* __restrict__ Whhf, const float* __restrict__ Whhb,
    const float* __restrict__ h0,
    unsigned short* __restrict__ tbl, unsigned short* __restrict__ wih,
    unsigned short* __restrict__ whh, unsigned short* __restrict__ hA,
    unsigned int* __restrict__ bar)
{
  const int gid = blockIdx.x * 256 + threadIdx.x;
  if (gid < 512) bar[gid] = 0;
  constexpr int NT  = cV * cE / 4;        // 3,840,000
  constexpr int NI  = cNG * cE / 4;       // 131,072
  constexpr int NH  = cNG * cHD / 4;      // 65,536
  constexpr int NH0 = 2 * cB * cHD / 4;   // 32,768
  constexpr int total = NT + 2*NI + 2*NH + NH0;
  for (int q = gid; q < total; q += 4096 * 256) {
    const float* src; unsigned short* dst; int lq;
    if (q < NT)             { src = embed; dst = tbl; lq = q; }
    else if (q < NT+NI)     { src = Wihf; dst = wih;             lq = q-NT; }
    else if (q < NT+2*NI)   { src = Wihb; dst = wih + cNG*cE;    lq = q-NT-NI; }
    else if (q < NT+2*NI+NH){ src = Whhf; dst = whh;             lq = q-NT-2*NI; }
    else if (q < NT+2*NI+2*NH){ src = Whhb; dst = whh + cNG*cHD; lq = q-NT-2*NI-NH; }
    else                    { src = h0;   dst = hA;              lq = q-NT-2*NI-2*NH; }
    const float4 v = *(const float4*)(src + (size_t)lq * 4);
    ushort4 u;
    u.x = f2bf(v.x); u.y = f2bf(v.y); u.z = f2bf(v.z); u.w = f2bf(v.w);
    *(ushort4*)(dst + (size_t)lq * 4) = u;
  }
}

// ---------------------------------------------------------------------------
// Embed projection, bf16 inputs, global_load_lds width-16 staging (m97 style).
// P[m][n] = sum_k tbl[ids(m)][k]*Wih[n][k] + b1[n]+b2[n]  (bf16 out)
// Tile 128x128, BK=64. XCD-aware 1D remap (same as R3).
// ---------------------------------------------------------------------------
__global__ __launch_bounds__(256) void k_embed_mfma(
    const int* __restrict__ ids,
    const unsigned short* __restrict__ tbl,   // [30000][512] bf16
    const unsigned short* __restrict__ Wih,   // [2][1024][512] bf16
    const float* __restrict__ b1f, const float* __restrict__ b2f,
    const float* __restrict__ b1b, const float* __restrict__ b2b,
    __hip_bfloat16* __restrict__ Pf, __hip_bfloat16* __restrict__ Pb)
{
  const int bid = blockIdx.x;
  const int xcd = bid & 7;
  const int jj  = bid >> 3;
  const int m_tile = xcd * 32 + (jj >> 4);
  const int nz  = jj & 15;
  const int n_tile = nz & 7;
  const int d   = nz >> 3;

  const unsigned short* W = Wih + (size_t)d * cNG * cE;
  const float* b1 = d ? b1b : b1f;
  const float* b2 = d ? b2b : b2f;
  unsigned short* P = (unsigned short*)(d ? Pb : Pf);

  const int n0 = n_tile * 128;
  const int m0 = m_tile * 128;
  const int tid = threadIdx.x;

  __shared__ unsigned short Al[128 * 64];
  __shared__ unsigned short Bl[128 * 64];
  __shared__ float bias_s[128];
  if (tid < 128) bias_s[tid] = b1[n0 + tid] + b2[n0 + tid];

  const int lane = tid & 63, wave = tid >> 6;
  const int wm = wave >> 1, wn = wave & 1;
  const int fr = lane & 15, fq = lane >> 4;

  // staging: wave stages rows [wave*32, wave*32+32) in 4 instrs of 8 rows
  const int srow = wave * 32;
  const int lrow = lane >> 3;     // 0..7
  const int lch  = lane & 7;      // 0..7  (16B chunk)
  int aid[4];
#pragma unroll
  for (int q = 0; q < 4; ++q) {
    const int m = m0 + srow + q * 8 + lrow;
    aid[q] = ids[(m & (cB - 1)) * cS + (m >> 8)];
  }

  f32x4 acc[4][4];
#pragma unroll
  for (int i = 0; i < 4; ++i)
#pragma unroll
    for (int j = 0; j < 4; ++j) acc[i][j] = (f32x4){0.f, 0.f, 0.f, 0.f};

  for (int kt = 0; kt < cE / 64; ++kt) {
    __syncthreads();   // prior mfma reads done before overwrite
#pragma unroll
    for (int q = 0; q < 4; ++q) {
      const unsigned short* ga = tbl + (size_t)aid[q] * cE + kt * 64 + lch * 8;
      const unsigned short* gb = W + (size_t)(n0 + srow + q * 8 + lrow) * cE + kt * 64 + lch * 8;
      gload_lds16(ga, Al + (srow + q * 8) * 64);
      gload_lds16(gb, Bl + (srow + q * 8) * 64);
    }
    __syncthreads();
#pragma unroll
    for (int ks = 0; ks < 2; ++ks) {
      bf16x8 aF[4], bF[4];
#pragma unroll
      for (int i = 0; i < 4; ++i)
        aF[i] = *(const bf16x8*)(Al + (wm * 64 + i * 16 + fr) * 64 + ks * 32 + fq * 8);
#pragma unroll
      for (int j = 0; j < 4; ++j)
        bF[j] = *(const bf16x8*)(Bl + (wn * 64 + j * 16 + fr) * 64 + ks * 32 + fq * 8);
#pragma unroll
      for (int i = 0; i < 4; ++i)
#pragma unroll
        for (int j = 0; j < 4; ++j)
          acc[i][j] = __builtin_amdgcn_mfma_f32_16x16x32_bf16(aF[i], bF[j], acc[i][j], 0, 0, 0);
    }
  }

#pragma unroll
  for (int i = 0; i < 4; ++i)
#pragma unroll
    for (int j = 0; j < 4; ++j) {
      const int gcol = wn * 64 + j * 16 + fr;
#pragma unroll
      for (int r = 0; r < 4; ++r) {
        const int grow = m0 + wm * 64 + i * 16 + fq * 4 + r;
        P[(size_t)grow * cNG + n0 + gcol] = f2bf(acc[i][j][r] + bias_s[gcol]);
      }
    }
}

// ---------------------------------------------------------------------------
// Persistent LSTM: ONE launch, 256 one-wave blocks, all 128 steps.
// Group = (dir, 32-batch-tile) = 16 blocks sharing h; group barrier via
// monotone device-scope counter (count>=16(t+1) iff ALL members finished t).
// bid = member*16 + group  => all members of a group share bid%8 (same XCD).
// W_hh fragments (128 VGPR) and c (8 VGPR) loop-resident in registers.
// ---------------------------------------------------------------------------
__global__ __launch_bounds__(64, 1) void k_lstm_all(
    const unsigned short* __restrict__ Wbf,   // [2][1024][256] bf16
    const unsigned short* __restrict__ Pf_,
    const unsigned short* __restrict__ Pb_,
    const float* __restrict__ c0,             // [2][256][256] f32
    unsigned short* __restrict__ hA,          // [2][256][256] bf16 (init h0)
    unsigned short* __restrict__ hB,
    float* __restrict__ feats,                // [S][B][H] f32
    unsigned int* __restrict__ bar)           // 16 counters, stride 32 uints
{
  const int bid = blockIdx.x;
  const int g   = bid & 15;            // group
  const int m_  = bid >> 4;            // member = j-tile
  const int d   = g >> 3;
  const int b0  = (g & 7) * 32;
  const int j0  = m_ * 16;
  const int lane = threadIdx.x;
  const int fr = lane & 15, fq = lane >> 4;
  const int jj = j0 + fr;
  const int hoff = d * (cB * cHD);
  unsigned int* cnt = bar + g * 32;

  const unsigned short* P = d ? Pb_ : Pf_;
  const unsigned short* wbase = Wbf + (size_t)d * cNG * cHD;

  // W fragments resident in registers: wreg[k0][gate]
  bf16x8 wreg[8][4];
#pragma unroll
  for (int k0 = 0; k0 < 8; ++k0)
#pragma unroll
    for (int gg = 0; gg < 4; ++gg)
      wreg[k0][gg] = *(const bf16x8*)(wbase + (size_t)(gg * cHD + j0 + fr) * cHD + k0 * 32 + fq * 8);

  // c resident in registers: creg[mf*4+r] for b = b0+mf*16+fq*4+r
  float creg[8];
#pragma unroll
  for (int mf = 0; mf < 2; ++mf)
#pragma unroll
    for (int r = 0; r < 4; ++r)
      creg[mf * 4 + r] = c0[hoff + (b0 + mf * 16 + fq * 4 + r) * cHD + jj];

  for (int t = 0; t < cS; ++t) {
    const int te = d ? (cS - 1 - t) : t;
    const unsigned short* hsrc = ((t & 1) ? hB : hA) + hoff;
    unsigned short* hdst = ((t & 1) ? hA : hB) + hoff;

    // A-frag loads first (L2, short latency; vmcnt retires in order so
    // issuing them before the HBM P loads keeps MFMA from waiting on P)
    bf16x8 areg[2][8];
#pragma unroll
    for (int k0 = 0; k0 < 8; ++k0) {
      areg[0][k0] = *(const bf16x8*)(hsrc + (b0 + fr) * cHD + k0 * 32 + fq * 8);
      areg[1][k0] = *(const bf16x8*)(hsrc + (b0 + 16 + fr) * cHD + k0 * 32 + fq * 8);
    }
    // P prefetch (precomputed; HBM/L3 latency overlaps MFMA)
    unsigned short pv[4][8];
    const unsigned short* Pt = P + (size_t)te * cB * cNG;
#pragma unroll
    for (int gg = 0; gg < 4; ++gg)
#pragma unroll
      for (int mf = 0; mf < 2; ++mf)
#pragma unroll
        for (int r = 0; r < 4; ++r)
          pv[gg][mf * 4 + r] = Pt[(size_t)(b0 + mf * 16 + fq * 4 + r) * cNG + gg * cHD + jj];

    f32x4 acc[2][4];
#pragma unroll
    for (int mf = 0; mf < 2; ++mf)
#pragma unroll
      for (int gg = 0; gg < 4; ++gg) acc[mf][gg] = (f32x4){0.f, 0.f, 0.f, 0.f};
#pragma unroll
    for (int k0 = 0; k0 < 8; ++k0)
#pragma unroll
      for (int gg = 0; gg < 4; ++gg) {
        acc[0][gg] = __builtin_amdgcn_mfma_f32_16x16x32_bf16(areg[0][k0], wreg[k0][gg], acc[0][gg], 0, 0, 0);
        acc[1][gg] = __builtin_amdgcn_mfma_f32_16x16x32_bf16(areg[1][k0], wreg[k0][gg], acc[1][gg], 0, 0, 0);
      }

#pragma unroll
    for (int mf = 0; mf < 2; ++mf)
#pragma unroll
      for (int r = 0; r < 4; ++r) {
        const int b = b0 + mf * 16 + fq * 4 + r;
        const float zi = acc[mf][0][r] + bf2f(pv[0][mf * 4 + r]);
        const float zf = acc[mf][1][r] + bf2f(pv[1][mf * 4 + r]);
        const float zg = acc[mf][2][r] + bf2f(pv[2][mf * 4 + r]);
        const float zo = acc[mf][3][r] + bf2f(pv[3][mf * 4 + r]);
        const float cc = fsig(zf) * creg[mf * 4 + r] + fsig(zi) * ftanh_(zg);
        creg[mf * 4 + r] = cc;
        const float h = fsig(zo) * ftanh_(cc);
        hdst[b * cHD + jj] = f2bf(h);
        feats[((size_t)te * cB + b) * cH + d * cHD + jj] = h;
      }

    if (t != cS - 1) {
      __threadfence();                               // release h stores (agent)
      if (lane == 0) {
        __hip_atomic_fetch_add(cnt, 1u, __ATOMIC_RELEASE, __HIP_MEMORY_SCOPE_AGENT);
        const unsigned int target = 16u * (unsigned int)(t + 1);
        while (__hip_atomic_load(cnt, __ATOMIC_ACQUIRE, __HIP_MEMORY_SCOPE_AGENT) < target)
          __builtin_amdgcn_s_sleep(1);
      }
      __threadfence();                               // acquire for all lanes
    }
  }
}

// ---------------------------------------------------------------------------
// GEMM 3: em[m][n] = sum_k feats[m][k] * W_out[n][k] + b_out[n]  (f32 out)
// ---------------------------------------------------------------------------
__global__ __launch_bounds__(256) void k_em_gemm(
    const float* __restrict__ A, const float* __restrict__ W,
    const float* __restrict__ bias, float* __restrict__ C)
{
  __shared__ float As[16][68];
  __shared__ float Bs[16][68];
  const int tid = threadIdx.x;
  const int tx = tid & 15, ty = tid >> 4;
  const int m0 = blockIdx.y * 64, n0 = blockIdx.x * 64;
  const int lm = tid >> 2;
  const int lk = (tid & 3) * 4;
  const float* arow = A + (size_t)(m0 + lm) * cH;
  const int nrow = n0 + lm;
  const bool bval = nrow < cT;
  const float* brow = W + (size_t)(bval ? nrow : 0) * cH;
  float acc[4][4] = {};
  for (int k0 = 0; k0 < cH; k0 += 16) {
    const float4 av = *(const float4*)(arow + k0 + lk);
    float4 bv = make_float4(0.f,0.f,0.f,0.f);
    if (bval) bv = *(const float4*)(brow + k0 + lk);
    __syncthreads();
    As[lk+0][lm]=av.x; As[lk+1][lm]=av.y; As[lk+2][lm]=av.z; As[lk+3][lm]=av.w;
    Bs[lk+0][lm]=bv.x; Bs[lk+1][lm]=bv.y; Bs[lk+2][lm]=bv.z; Bs[lk+3][lm]=bv.w;
    __syncthreads();
#pragma unroll
    for (int kk = 0; kk < 16; ++kk) {
      const float4 a4 = *(const float4*)(&As[kk][ty*4]);
      const float4 b4 = *(const float4*)(&Bs[kk][tx*4]);
      const float a[4] = {a4.x,a4.y,a4.z,a4.w};
      const float b[4] = {b4.x,b4.y,b4.z,b4.w};
#pragma unroll
      for (int i=0;i<4;++i)
#pragma unroll
        for (int j=0;j<4;++j) acc[i][j] += a[i]*b[j];
    }
  }
#pragma unroll
  for (int i=0;i<4;++i) {
    const int mrow = m0 + ty*4 + i;
#pragma unroll
    for (int j=0;j<4;++j) {
      const int n = n0 + tx*4 + j;
      if (n < cT) C[(size_t)mrow * cT + n] = acc[i][j] + bias[n];
    }
  }
}

// ---------------------------------------------------------------------------
// CRF: one block per batch element, 320 threads (5 waves). (unchanged R2)
// ---------------------------------------------------------------------------
__global__ __launch_bounds__(320) void k_crf(
    const float* __restrict__ em,       // (S,B,T)
    const int* __restrict__ tag_ids,    // (B,S)
    const int* __restrict__ lengths,    // (B,)
    const float* __restrict__ start_trans,
    const float* __restrict__ end_trans,
    const float* __restrict__ trans,    // (T,T)
    float* __restrict__ llh)            // (B,)
{
  const int b = blockIdx.x;
  const int tid = threadIdx.x;
  const int len = lengths[b];

  __shared__ float trans_t[80 * 81];    // [j][i], stride 81
  __shared__ float em_s[cS * 80];       // [t][j], stride 80
  __shared__ float a0[80], a1[80];
  __shared__ float red[128];
  __shared__ float score_sh;

  for (int idx = tid; idx < cT * cT; idx += 320) {
    const int i = idx / cT, jt = idx - i * cT;
    trans_t[jt * 81 + i] = trans[idx];
  }
  for (int idx = tid; idx < cS * cT; idx += 320) {
    const int t = idx / cT, jt = idx - t * cT;
    em_s[t * 80 + jt] = em[((size_t)t * cB + b) * cT + jt];
  }
  __syncthreads();

  float contrib = 0.f;
  if (tid < cS) {
    const int t = tid;
    if (t == 0) {
      const int tg = tag_ids[b * cS];
      contrib = start_trans[tg] + em_s[tg];
    } else if (t < len) {
      const int tg = tag_ids[b * cS + t];
      const int tp = tag_ids[b * cS + t - 1];
      contrib = trans_t[tg * 81 + tp] + em_s[t * 80 + tg];
    }
    if (t == len - 1) contrib += end_trans[tag_ids[b * cS + len - 1]];
  }
  if (tid < 128) red[tid] = contrib;
  __syncthreads();
  for (int s = 64; s > 0; s >>= 1) {
    if (tid < s) red[tid] += red[tid + s];
    __syncthreads();
  }
  if (tid == 0) score_sh = red[0];

  const int j   = tid >> 2;
  const int sub = tid & 3;
  const int i0  = sub * 19;
  float* cur = a0;
  float* nxt = a1;
  if (sub == 0 && j < cT) cur[j] = start_trans[j] + em_s[j];
  __syncthreads();
  for (int t = 1; t < len; ++t) {
    const float mref = cur[0];
    const float* trow = &trans_t[j * 81 + i0];
    const float* crow = &cur[i0];
    float s = 0.f;
#pragma unroll
    for (int q = 0; q < 19; ++q)
      s += __expf(crow[q] + trow[q] - mref);
    s += __shfl_xor(s, 1);
    s += __shfl_xor(s, 2);
    if (sub == 0 && j < cT) nxt[j] = mref + __logf(s) + em_s[t * 80 + j];
    __syncthreads();
    float* tp2 = cur; cur = nxt; nxt = tp2;
  }

  const float v = (tid < cT) ? cur[tid] + end_trans[tid] : -1e30f;
  if (tid < 128) red[tid] = v;
  __syncthreads();
  for (int s = 64; s > 0; s >>= 1) {
    if (tid < s) red[tid] = fmaxf(red[tid], red[tid + s]);
    __syncthreads();
  }
  const float mx = red[0];
  __syncthreads();
  if (tid < 128) red[tid] = (tid < cT) ? __expf(v - mx) : 0.f;
  __syncthreads();
  for (int s = 64; s > 0; s >>= 1) {
    if (tid < s) red[tid] += red[tid + s];
    __syncthreads();
  }
  if (tid == 0) llh[b] = score_sh - (mx + __logf(red[0]));
}

__global__ __launch_bounds__(256) void k_final(const float* __restrict__ llh,
                                               float* __restrict__ out)
{
  __shared__ float red[256];
  const int tid = threadIdx.x;
  red[tid] = llh[tid];
  __syncthreads();
  for (int s = 128; s > 0; s >>= 1) {
    if (tid < s) red[tid] += red[tid + s];
    __syncthreads();
  }
  if (tid == 0) out[0] = -red[0] * (1.0f / cB);
}

} // anonymous namespace

extern "C" void kernel_launch(void* const* d_in, const int* in_sizes, int n_in,
                              void* d_out, int out_size, void* d_ws, size_t ws_size,
                              hipStream_t stream) {
  const int*   input_ids   = (const int*)  d_in[0];
  const int*   tag_ids     = (const int*)  d_in[1];
  const int*   lengths     = (const int*)  d_in[2];
  const float* embed_table = (const float*)d_in[3];
  const float* W_ih_f      = (const float*)d_in[4];
  const float* W_hh_f      = (const float*)d_in[5];
  const float* b_ih_f      = (const float*)d_in[6];
  const float* b_hh_f      = (const float*)d_in[7];
  const float* W_ih_b      = (const float*)d_in[8];
  const float* W_hh_b      = (const float*)d_in[9];
  const float* b_ih_b      = (const float*)d_in[10];
  const float* b_hh_b      = (const float*)d_in[11];
  const float* W_out       = (const float*)d_in[12];
  const float* b_out       = (const float*)d_in[13];
  const float* start_trans = (const float*)d_in[14];
  const float* end_trans   = (const float*)d_in[15];
  const float* trans       = (const float*)d_in[16];
  const float* h0          = (const float*)d_in[17];
  const float* c0          = (const float*)d_in[18];
  float* out = (float*)d_out;

  // workspace layout (lifetime-aliased):
  //  [0, 128MiB)            P (bf16, both dirs)  -- after LSTM, reused for em (f32)
  //  [128MiB, 192MiB)       feats (f32)          -- before LSTM, holds tbl_bf + wih_bf
  //  then: whh_bf, hA, hB, llh, barriers
  char* wsb = (char*)d_ws;
  const size_t szP     = (size_t)cM * cNG * sizeof(unsigned short); // 64 MiB each
  const size_t szFeats = (size_t)cM * cH * sizeof(float);           // 64 MiB
  __hip_bfloat16* Pf = (__hip_bfloat16*)(wsb);
  __hip_bfloat16* Pb = (__hip_bfloat16*)(wsb + szP);
  float* em    = (float*)(wsb);                      // aliases P (post-LSTM)
  float* feats = (float*)(wsb + 2 * szP);
  unsigned short* tbl = (unsigned short*)(wsb + 2 * szP);            // aliases feats (pre-LSTM)
  unsigned short* wih = tbl + (size_t)cV * cE;                       // 30.72MB in
  char* p = wsb + 2 * szP + szFeats;
  unsigned short* whh = (unsigned short*)p;  p += (size_t)2 * cNG * cHD * sizeof(unsigned short);
  unsigned short* hA  = (unsigned short*)p;  p += (size_t)2 * cB * cHD * sizeof(unsigned short);
  unsigned short* hB  = (unsigned short*)p;  p += (size_t)2 * cB * cHD * sizeof(unsigned short);
  float* llh          = (float*)p;           p += 1024;
  unsigned int* bar   = (unsigned int*)p;    // 512 uints (16 groups * 32 stride)

  // 0) prep: bf16 conversions + barrier zeroing
  k_prep<<<4096, 256, 0, stream>>>(embed_table, W_ih_f, W_ih_b, W_hh_f, W_hh_b,
                                   h0, tbl, wih, whh, hA, bar);

  // 1) input projections (gather GEMM), bf16 MFMA + global_load_lds staging
  k_embed_mfma<<<4096, 256, 0, stream>>>(input_ids, tbl, wih,
                                         b_ih_f, b_hh_f, b_ih_b, b_hh_b, Pf, Pb);

  // 2) full recurrence in ONE persistent kernel (group barriers inside)
  k_lstm_all<<<256, 64, 0, stream>>>(whh, (const unsigned short*)Pf,
                                     (const unsigned short*)Pb,
                                     c0, hA, hB, feats, bar);

  // 3) emissions (em aliases the now-dead P region)
  dim3 g3((cT + 63) / 64, cM / 64);
  k_em_gemm<<<g3, 256, 0, stream>>>(feats, W_out, b_out, em);

  // 4) CRF per batch element + final mean
  k_crf<<<cB, 320, 0, stream>>>(em, tag_ids, lengths, start_trans, end_trans, trans, llh);
  k_final<<<1, 256, 0, stream>>>(llh, out);
}

// Round 5
// 823.260 us; speedup vs baseline: 2.9405x; 2.9405x over previous
//
#include <hip/hip_runtime.h>
#include <hip/hip_bf16.h>
#include <math.h>

namespace {

constexpr int cE  = 512;    // embed dim
constexpr int cH  = 512;    // total hidden (2 dirs)
constexpr int cT  = 76;     // tags
constexpr int cB  = 256;    // batch
constexpr int cS  = 128;    // seq len
constexpr int cHD = 256;    // per-dir hidden
constexpr int cNG = 1024;   // 4*HD gate width
constexpr int cM  = cS * cB; // 32768 rows of (S,B) flattened
constexpr int cV  = 30000;  // vocab
constexpr int cBH = cB * cHD; // 65536

typedef __attribute__((ext_vector_type(8))) short bf16x8;
typedef __attribute__((ext_vector_type(4))) float f32x4;
typedef unsigned long long ull_t;

typedef const __attribute__((address_space(1))) unsigned int* gas_ptr;
typedef __attribute__((address_space(3))) unsigned int* las_ptr;

__device__ __forceinline__ float fsig(float x) { return 1.0f / (1.0f + __expf(-x)); }
__device__ __forceinline__ float ftanh_(float x) {
  float e = __expf(2.0f * fabsf(x));
  float t = 1.0f - 2.0f / (e + 1.0f);
  return copysignf(t, x);
}
__device__ __forceinline__ unsigned short f2bf(float f) {
  __hip_bfloat16 h = __float2bfloat16(f);
  return *reinterpret_cast<unsigned short*>(&h);
}
__device__ __forceinline__ float bf2f(unsigned short u) {
  unsigned int v = ((unsigned int)u) << 16;
  return *reinterpret_cast<float*>(&v);
}
__device__ __forceinline__ void gload_lds16(const void* g, void* l) {
  __builtin_amdgcn_global_load_lds((gas_ptr)g, (las_ptr)l, 16, 0, 0);
}

// ---------------------------------------------------------------------------
// Prep: bf16-convert embed table, W_ih(2), W_hh(2), h0; W_out zero-padded to
// 128 rows; zero barriers. Vectorized float4 -> ushort4 grid-stride.
// ---------------------------------------------------------------------------
__global__ __launch_bounds__(256) void k_prep(
    const float* __restrict__ embed,
    const float* __restrict__ Wihf, const float* __restrict__ Wihb,
    const float* __restrict__ Whhf, const float* __restrict__ Whhb,
    const float* __restrict__ h0,   const float* __restrict__ Wout,
    unsigned short* __restrict__ tbl, unsigned short* __restrict__ wih,
    unsigned short* __restrict__ whh, unsigned short* __restrict__ hInit,
    unsigned short* __restrict__ WoutP, unsigned int* __restrict__ bar)
{
  const int gid = blockIdx.x * 256 + threadIdx.x;
  if (gid < 512) bar[gid] = 0;
  constexpr int NT  = cV * cE / 4;        // 3,840,000
  constexpr int NI  = cNG * cE / 4;       // 131,072
  constexpr int NH  = cNG * cHD / 4;      // 65,536
  constexpr int NH0 = 2 * cBH / 4;        // 32,768
  constexpr int NW  = 128 * cE / 4;       // 16,384 (padded W_out)
  constexpr int total = NT + 2*NI + 2*NH + NH0 + NW;
  for (int q = gid; q < total; q += 4096 * 256) {
    const float* src; unsigned short* dst; int lq;
    bool zero = false;
    if (q < NT)               { src = embed; dst = tbl;              lq = q; }
    else if (q < NT+NI)       { src = Wihf;  dst = wih;              lq = q-NT; }
    else if (q < NT+2*NI)     { src = Wihb;  dst = wih + cNG*cE;     lq = q-NT-NI; }
    else if (q < NT+2*NI+NH)  { src = Whhf;  dst = whh;              lq = q-NT-2*NI; }
    else if (q < NT+2*NI+2*NH){ src = Whhb;  dst = whh + cNG*cHD;    lq = q-NT-2*NI-NH; }
    else if (q < NT+2*NI+2*NH+NH0){ src = h0; dst = hInit;           lq = q-NT-2*NI-2*NH; }
    else { lq = q-NT-2*NI-2*NH-NH0; src = Wout; dst = WoutP; zero = (lq >= cT*cE/4); }
    float4 v = make_float4(0.f,0.f,0.f,0.f);
    if (!zero) v = *(const float4*)(src + (size_t)lq * 4);
    ushort4 u;
    u.x = f2bf(v.x); u.y = f2bf(v.y); u.z = f2bf(v.z); u.w = f2bf(v.w);
    *(ushort4*)(dst + (size_t)lq * 4) = u;
  }
}

// ---------------------------------------------------------------------------
// Embed projection (unchanged R4): bf16 MFMA + global_load_lds staging,
// XCD-aware 1D remap. P[m][n] = sum_k tbl[ids(m)][k]*Wih[n][k] + b1[n]+b2[n]
// ---------------------------------------------------------------------------
__global__ __launch_bounds__(256) void k_embed_mfma(
    const int* __restrict__ ids,
    const unsigned short* __restrict__ tbl,
    const unsigned short* __restrict__ Wih,
    const float* __restrict__ b1f, const float* __restrict__ b2f,
    const float* __restrict__ b1b, const float* __restrict__ b2b,
    __hip_bfloat16* __restrict__ Pf, __hip_bfloat16* __restrict__ Pb)
{
  const int bid = blockIdx.x;
  const int xcd = bid & 7;
  const int jj  = bid >> 3;
  const int m_tile = xcd * 32 + (jj >> 4);
  const int nz  = jj & 15;
  const int n_tile = nz & 7;
  const int d   = nz >> 3;

  const unsigned short* W = Wih + (size_t)d * cNG * cE;
  const float* b1 = d ? b1b : b1f;
  const float* b2 = d ? b2b : b2f;
  unsigned short* P = (unsigned short*)(d ? Pb : Pf);

  const int n0 = n_tile * 128;
  const int m0 = m_tile * 128;
  const int tid = threadIdx.x;

  __shared__ unsigned short Al[128 * 64];
  __shared__ unsigned short Bl[128 * 64];
  __shared__ float bias_s[128];
  if (tid < 128) bias_s[tid] = b1[n0 + tid] + b2[n0 + tid];

  const int lane = tid & 63, wave = tid >> 6;
  const int wm = wave >> 1, wn = wave & 1;
  const int fr = lane & 15, fq = lane >> 4;

  const int srow = wave * 32;
  const int lrow = lane >> 3;
  const int lch  = lane & 7;
  int aid[4];
#pragma unroll
  for (int q = 0; q < 4; ++q) {
    const int m = m0 + srow + q * 8 + lrow;
    aid[q] = ids[(m & (cB - 1)) * cS + (m >> 8)];
  }

  f32x4 acc[4][4];
#pragma unroll
  for (int i = 0; i < 4; ++i)
#pragma unroll
    for (int j = 0; j < 4; ++j) acc[i][j] = (f32x4){0.f, 0.f, 0.f, 0.f};

  for (int kt = 0; kt < cE / 64; ++kt) {
    __syncthreads();
#pragma unroll
    for (int q = 0; q < 4; ++q) {
      const unsigned short* ga = tbl + (size_t)aid[q] * cE + kt * 64 + lch * 8;
      const unsigned short* gb = W + (size_t)(n0 + srow + q * 8 + lrow) * cE + kt * 64 + lch * 8;
      gload_lds16(ga, Al + (srow + q * 8) * 64);
      gload_lds16(gb, Bl + (srow + q * 8) * 64);
    }
    __syncthreads();
#pragma unroll
    for (int ks = 0; ks < 2; ++ks) {
      bf16x8 aF[4], bF[4];
#pragma unroll
      for (int i = 0; i < 4; ++i)
        aF[i] = *(const bf16x8*)(Al + (wm * 64 + i * 16 + fr) * 64 + ks * 32 + fq * 8);
#pragma unroll
      for (int j = 0; j < 4; ++j)
        bF[j] = *(const bf16x8*)(Bl + (wn * 64 + j * 16 + fr) * 64 + ks * 32 + fq * 8);
#pragma unroll
      for (int i = 0; i < 4; ++i)
#pragma unroll
        for (int j = 0; j < 4; ++j)
          acc[i][j] = __builtin_amdgcn_mfma_f32_16x16x32_bf16(aF[i], bF[j], acc[i][j], 0, 0, 0);
    }
  }

#pragma unroll
  for (int i = 0; i < 4; ++i)
#pragma unroll
    for (int j = 0; j < 4; ++j) {
      const int gcol = wn * 64 + j * 16 + fr;
#pragma unroll
      for (int r = 0; r < 4; ++r) {
        const int grow = m0 + wm * 64 + i * 16 + fq * 4 + r;
        P[(size_t)grow * cNG + n0 + gcol] = f2bf(acc[i][j][r] + bias_s[gcol]);
      }
    }
}

// ---------------------------------------------------------------------------
// Persistent LSTM v2: barrier-lite. h exchanged through memory-side coherence
// point via RELAXED AGENT-scope 8B atomic loads/stores (sc1, no cache
// maintenance); ordering via __threadfence_block (waitcnt only — NO wbl2/inv).
// h history hHist[t][d][b][j] bf16 doubles as the em-GEMM input (no f32 feats).
// W_hh (128 VGPR) and c (8 VGPR) loop-resident. 256 one-wave blocks.
// Group = (d, b-tile32) = 16 blocks; monotone counter barrier.
// ---------------------------------------------------------------------------
__global__ __launch_bounds__(64, 1) void k_lstm_all(
    const unsigned short* __restrict__ Wbf,   // [2][1024][256] bf16
    const unsigned short* __restrict__ Pf_,
    const unsigned short* __restrict__ Pb_,
    const float* __restrict__ c0,             // [2][256][256] f32
    const unsigned short* __restrict__ hInit, // [2][256][256] bf16
    ull_t* __restrict__ hHist,                // [S][2][256][256] bf16 (as ull)
    unsigned int* __restrict__ bar)           // 16 counters, stride 32 uints
{
  const int bid = blockIdx.x;
  const int g   = bid & 15;            // group
  const int m_  = bid >> 4;            // member = j-tile
  const int d   = g >> 3;
  const int b0  = (g & 7) * 32;
  const int j0  = m_ * 16;
  const int lane = threadIdx.x;
  const int fr = lane & 15, fq = lane >> 4;
  const int jj = j0 + fr;
  unsigned int* cnt = bar + g * 32;

  const unsigned short* P = d ? Pb_ : Pf_;
  const unsigned short* wbase = Wbf + (size_t)d * cNG * cHD;

  // W fragments resident in registers
  bf16x8 wreg[8][4];
#pragma unroll
  for (int k0 = 0; k0 < 8; ++k0)
#pragma unroll
    for (int gg = 0; gg < 4; ++gg)
      wreg[k0][gg] = *(const bf16x8*)(wbase + (size_t)(gg * cHD + j0 + fr) * cHD + k0 * 32 + fq * 8);

  // c resident in registers
  float creg[8];
#pragma unroll
  for (int mf = 0; mf < 2; ++mf)
#pragma unroll
    for (int r = 0; r < 4; ++r)
      creg[mf * 4 + r] = c0[d * cBH + (b0 + mf * 16 + fq * 4 + r) * cHD + jj];

  __shared__ unsigned short hs[32 * 16];   // epilogue transpose staging

  for (int t = 0; t < cS; ++t) {
    const int te = d ? (cS - 1 - t) : t;

    // ---- A-fragment loads: relaxed agent atomics (memory-side, always fresh)
    const ull_t* hsrc;
    if (t == 0) {
      hsrc = (const ull_t*)hInit + ((size_t)d * cBH >> 2);
    } else {
      const int tp = d ? (te + 1) : (te - 1);
      hsrc = hHist + ((((size_t)tp * 2 + d) * cBH) >> 2);
    }
    bf16x8 areg[2][8];
#pragma unroll
    for (int mf = 0; mf < 2; ++mf)
#pragma unroll
      for (int k0 = 0; k0 < 8; ++k0) {
        const size_t base = (((size_t)(b0 + mf * 16 + fr) * cHD + k0 * 32 + fq * 8) >> 2);
        union { ull_t u[2]; bf16x8 v; } tmp;
        tmp.u[0] = __hip_atomic_load((ull_t*)(hsrc + base),     __ATOMIC_RELAXED, __HIP_MEMORY_SCOPE_AGENT);
        tmp.u[1] = __hip_atomic_load((ull_t*)(hsrc + base + 1), __ATOMIC_RELAXED, __HIP_MEMORY_SCOPE_AGENT);
        areg[mf][k0] = tmp.v;
      }

    // ---- P prefetch (read-only precomputed data; normal loads)
    unsigned short pv[4][8];
    const unsigned short* Pt = P + (size_t)te * cB * cNG;
#pragma unroll
    for (int gg = 0; gg < 4; ++gg)
#pragma unroll
      for (int mf = 0; mf < 2; ++mf)
#pragma unroll
        for (int r = 0; r < 4; ++r)
          pv[gg][mf * 4 + r] = Pt[(size_t)(b0 + mf * 16 + fq * 4 + r) * cNG + gg * cHD + jj];

    // ---- MFMA: M=32, N=16(x4 gates), K=256
    f32x4 acc[2][4];
#pragma unroll
    for (int mf = 0; mf < 2; ++mf)
#pragma unroll
      for (int gg = 0; gg < 4; ++gg) acc[mf][gg] = (f32x4){0.f, 0.f, 0.f, 0.f};
#pragma unroll
    for (int k0 = 0; k0 < 8; ++k0)
#pragma unroll
      for (int gg = 0; gg < 4; ++gg) {
        acc[0][gg] = __builtin_amdgcn_mfma_f32_16x16x32_bf16(areg[0][k0], wreg[k0][gg], acc[0][gg], 0, 0, 0);
        acc[1][gg] = __builtin_amdgcn_mfma_f32_16x16x32_bf16(areg[1][k0], wreg[k0][gg], acc[1][gg], 0, 0, 0);
      }

    // ---- gates -> h (bf16) into LDS (transpose to packed rows)
#pragma unroll
    for (int mf = 0; mf < 2; ++mf)
#pragma unroll
      for (int r = 0; r < 4; ++r) {
        const float zi = acc[mf][0][r] + bf2f(pv[0][mf * 4 + r]);
        const float zf = acc[mf][1][r] + bf2f(pv[1][mf * 4 + r]);
        const float zg = acc[mf][2][r] + bf2f(pv[2][mf * 4 + r]);
        const float zo = acc[mf][3][r] + bf2f(pv[3][mf * 4 + r]);
        const float cc = fsig(zf) * creg[mf * 4 + r] + fsig(zi) * ftanh_(zg);
        creg[mf * 4 + r] = cc;
        hs[(mf * 16 + fq * 4 + r) * 16 + fr] = f2bf(fsig(zo) * ftanh_(cc));
      }

    // ---- packed 8B atomic stores of the 32x16 h slice (2 per lane)
    {
      const int row = lane >> 1, half = lane & 1;
      const ull_t v0 = *(const ull_t*)(hs + row * 16 + half * 8);
      const ull_t v1 = *(const ull_t*)(hs + row * 16 + half * 8 + 4);
      const size_t idx = ((((size_t)te * 2 + d) * cBH) + (b0 + row) * cHD + j0 + half * 8) >> 2;
      __hip_atomic_store(hHist + idx,     v0, __ATOMIC_RELAXED, __HIP_MEMORY_SCOPE_AGENT);
      __hip_atomic_store(hHist + idx + 1, v1, __ATOMIC_RELAXED, __HIP_MEMORY_SCOPE_AGENT);
    }

    // ---- group barrier: waitcnt-only fences + relaxed monotone counter
    if (t != cS - 1) {
      __threadfence_block();   // s_waitcnt vmcnt(0): h stores at coherence pt
      if (lane == 0) {
        __hip_atomic_fetch_add(cnt, 1u, __ATOMIC_RELAXED, __HIP_MEMORY_SCOPE_AGENT);
        const unsigned int target = 16u * (unsigned int)(t + 1);
        while (__hip_atomic_load(cnt, __ATOMIC_RELAXED, __HIP_MEMORY_SCOPE_AGENT) < target)
          __builtin_amdgcn_s_sleep(1);
      }
      __threadfence_block();   // order next-step A loads after poll
    }
  }
}

// ---------------------------------------------------------------------------
// Emissions: bf16 MFMA. em[m][n] = sum_k hfeat[m][k]*WoutP[n][k] + b_out[n]
// A = hHist ([t][d][b][j] -> row m=t*256+b, k=d*256+j). N padded to 128.
// ---------------------------------------------------------------------------
__global__ __launch_bounds__(256) void k_em_mfma(
    const unsigned short* __restrict__ hHist,  // [S][2][256][256] bf16
    const unsigned short* __restrict__ WoutP,  // [128][512] bf16 (rows>=76 = 0)
    const float* __restrict__ b_out, float* __restrict__ em)
{
  const int m0 = blockIdx.x * 128;
  const int tid = threadIdx.x;

  __shared__ unsigned short Al[128 * 64];
  __shared__ unsigned short Bl[128 * 64];
  __shared__ float bias_s[128];
  if (tid < 128) bias_s[tid] = (tid < cT) ? b_out[tid] : 0.f;

  const int lane = tid & 63, wave = tid >> 6;
  const int wm = wave >> 1, wn = wave & 1;
  const int fr = lane & 15, fq = lane >> 4;
  const int srow = wave * 32;
  const int lrow = lane >> 3;
  const int lch  = lane & 7;

  f32x4 acc[4][4];
#pragma unroll
  for (int i = 0; i < 4; ++i)
#pragma unroll
    for (int j = 0; j < 4; ++j) acc[i][j] = (f32x4){0.f, 0.f, 0.f, 0.f};

  for (int kt = 0; kt < 8; ++kt) {
    const int d  = kt >> 2;
    const int ko = (kt & 3) * 64;
    __syncthreads();
#pragma unroll
    for (int q = 0; q < 4; ++q) {
      const int row = srow + q * 8 + lrow;
      const int m = m0 + row;
      const int t = m >> 8, b = m & 255;
      const unsigned short* ga = hHist + (((size_t)t * 2 + d) * cB + b) * cHD + ko + lch * 8;
      const unsigned short* gb = WoutP + (size_t)row * cH + kt * 64 + lch * 8;
      gload_lds16(ga, Al + (srow + q * 8) * 64);
      gload_lds16(gb, Bl + (srow + q * 8) * 64);
    }
    __syncthreads();
#pragma unroll
    for (int ks = 0; ks < 2; ++ks) {
      bf16x8 aF[4], bF[4];
#pragma unroll
      for (int i = 0; i < 4; ++i)
        aF[i] = *(const bf16x8*)(Al + (wm * 64 + i * 16 + fr) * 64 + ks * 32 + fq * 8);
#pragma unroll
      for (int j = 0; j < 4; ++j)
        bF[j] = *(const bf16x8*)(Bl + (wn * 64 + j * 16 + fr) * 64 + ks * 32 + fq * 8);
#pragma unroll
      for (int i = 0; i < 4; ++i)
#pragma unroll
        for (int j = 0; j < 4; ++j)
          acc[i][j] = __builtin_amdgcn_mfma_f32_16x16x32_bf16(aF[i], bF[j], acc[i][j], 0, 0, 0);
    }
  }

#pragma unroll
  for (int i = 0; i < 4; ++i)
#pragma unroll
    for (int j = 0; j < 4; ++j) {
      const int gcol = wn * 64 + j * 16 + fr;
      if (gcol < cT) {
#pragma unroll
        for (int r = 0; r < 4; ++r) {
          const int grow = m0 + wm * 64 + i * 16 + fq * 4 + r;
          em[(size_t)grow * cT + gcol] = acc[i][j][r] + bias_s[gcol];
        }
      }
    }
}

// ---------------------------------------------------------------------------
// CRF: one block per batch element, 320 threads (5 waves). (unchanged R2)
// ---------------------------------------------------------------------------
__global__ __launch_bounds__(320) void k_crf(
    const float* __restrict__ em,
    const int* __restrict__ tag_ids,
    const int* __restrict__ lengths,
    const float* __restrict__ start_trans,
    const float* __restrict__ end_trans,
    const float* __restrict__ trans,
    float* __restrict__ llh)
{
  const int b = blockIdx.x;
  const int tid = threadIdx.x;
  const int len = lengths[b];

  __shared__ float trans_t[80 * 81];
  __shared__ float em_s[cS * 80];
  __shared__ float a0[80], a1[80];
  __shared__ float red[128];
  __shared__ float score_sh;

  for (int idx = tid; idx < cT * cT; idx += 320) {
    const int i = idx / cT, jt = idx - i * cT;
    trans_t[jt * 81 + i] = trans[idx];
  }
  for (int idx = tid; idx < cS * cT; idx += 320) {
    const int t = idx / cT, jt = idx - t * cT;
    em_s[t * 80 + jt] = em[((size_t)t * cB + b) * cT + jt];
  }
  __syncthreads();

  float contrib = 0.f;
  if (tid < cS) {
    const int t = tid;
    if (t == 0) {
      const int tg = tag_ids[b * cS];
      contrib = start_trans[tg] + em_s[tg];
    } else if (t < len) {
      const int tg = tag_ids[b * cS + t];
      const int tp = tag_ids[b * cS + t - 1];
      contrib = trans_t[tg * 81 + tp] + em_s[t * 80 + tg];
    }
    if (t == len - 1) contrib += end_trans[tag_ids[b * cS + len - 1]];
  }
  if (tid < 128) red[tid] = contrib;
  __syncthreads();
  for (int s = 64; s > 0; s >>= 1) {
    if (tid < s) red[tid] += red[tid + s];
    __syncthreads();
  }
  if (tid == 0) score_sh = red[0];

  const int j   = tid >> 2;
  const int sub = tid & 3;
  const int i0  = sub * 19;
  float* cur = a0;
  float* nxt = a1;
  if (sub == 0 && j < cT) cur[j] = start_trans[j] + em_s[j];
  __syncthreads();
  for (int t = 1; t < len; ++t) {
    const float mref = cur[0];
    const float* trow = &trans_t[j * 81 + i0];
    const float* crow = &cur[i0];
    float s = 0.f;
#pragma unroll
    for (int q = 0; q < 19; ++q)
      s += __expf(crow[q] + trow[q] - mref);
    s += __shfl_xor(s, 1);
    s += __shfl_xor(s, 2);
    if (sub == 0 && j < cT) nxt[j] = mref + __logf(s) + em_s[t * 80 + j];
    __syncthreads();
    float* tp2 = cur; cur = nxt; nxt = tp2;
  }

  const float v = (tid < cT) ? cur[tid] + end_trans[tid] : -1e30f;
  if (tid < 128) red[tid] = v;
  __syncthreads();
  for (int s = 64; s > 0; s >>= 1) {
    if (tid < s) red[tid] = fmaxf(red[tid], red[tid + s]);
    __syncthreads();
  }
  const float mx = red[0];
  __syncthreads();
  if (tid < 128) red[tid] = (tid < cT) ? __expf(v - mx) : 0.f;
  __syncthreads();
  for (int s = 64; s > 0; s >>= 1) {
    if (tid < s) red[tid] += red[tid + s];
    __syncthreads();
  }
  if (tid == 0) llh[b] = score_sh - (mx + __logf(red[0]));
}

__global__ __launch_bounds__(256) void k_final(const float* __restrict__ llh,
                                               float* __restrict__ out)
{
  __shared__ float red[256];
  const int tid = threadIdx.x;
  red[tid] = llh[tid];
  __syncthreads();
  for (int s = 128; s > 0; s >>= 1) {
    if (tid < s) red[tid] += red[tid + s];
    __syncthreads();
  }
  if (tid == 0) out[0] = -red[0] * (1.0f / cB);
}

} // anonymous namespace

extern "C" void kernel_launch(void* const* d_in, const int* in_sizes, int n_in,
                              void* d_out, int out_size, void* d_ws, size_t ws_size,
                              hipStream_t stream) {
  const int*   input_ids   = (const int*)  d_in[0];
  const int*   tag_ids     = (const int*)  d_in[1];
  const int*   lengths     = (const int*)  d_in[2];
  const float* embed_table = (const float*)d_in[3];
  const float* W_ih_f      = (const float*)d_in[4];
  const float* W_hh_f      = (const float*)d_in[5];
  const float* b_ih_f      = (const float*)d_in[6];
  const float* b_hh_f      = (const float*)d_in[7];
  const float* W_ih_b      = (const float*)d_in[8];
  const float* W_hh_b      = (const float*)d_in[9];
  const float* b_ih_b      = (const float*)d_in[10];
  const float* b_hh_b      = (const float*)d_in[11];
  const float* W_out       = (const float*)d_in[12];
  const float* b_out       = (const float*)d_in[13];
  const float* start_trans = (const float*)d_in[14];
  const float* end_trans   = (const float*)d_in[15];
  const float* trans       = (const float*)d_in[16];
  const float* h0          = (const float*)d_in[17];
  const float* c0          = (const float*)d_in[18];
  float* out = (float*)d_out;

  // workspace layout (lifetime-aliased; ~180 MiB total):
  //  [0,64M)    Pf          [64M,128M) Pb
  //  [128M, +30.72M) tbl (embed-only)   ... hHist [128M, +32M) (lstm+em; tbl dead)
  //  [159M, +4M) wih (embed-only; dead when hHist written past 159M? hHist ends
  //             at 160M, wih spans [159M,163M) -> only used pre-lstm, safe)
  //  [164M, +9.96M) em f32 (post-lstm; tbl/wih dead)
  //  [176M ...) whh, hInit, WoutP, llh, bar (prep-written, never overlapped)
  char* wsb = (char*)d_ws;
  const size_t MB = 1024 * 1024;
  __hip_bfloat16* Pf = (__hip_bfloat16*)(wsb);
  __hip_bfloat16* Pb = (__hip_bfloat16*)(wsb + 64 * MB);
  unsigned short* tbl   = (unsigned short*)(wsb + 128 * MB);
  ull_t*          hHist = (ull_t*)         (wsb + 128 * MB);   // aliases tbl
  unsigned short* wih   = (unsigned short*)(wsb + 160 * MB);
  float*          em    = (float*)         (wsb + 165 * MB);
  unsigned short* whh   = (unsigned short*)(wsb + 176 * MB);   // 1 MiB
  unsigned short* hInit = (unsigned short*)(wsb + 177 * MB);   // 256 KiB
  unsigned short* WoutP = (unsigned short*)(wsb + 178 * MB);   // 128 KiB
  float*          llh   = (float*)         (wsb + 179 * MB);
  unsigned int*   bar   = (unsigned int*)  (wsb + 179 * MB + 4096);

  // 0) prep: bf16 conversions + padded W_out + barrier zeroing
  k_prep<<<4096, 256, 0, stream>>>(embed_table, W_ih_f, W_ih_b, W_hh_f, W_hh_b,
                                   h0, W_out, tbl, wih, whh, hInit, WoutP, bar);

  // 1) input projections (gather GEMM), bf16 MFMA + global_load_lds staging
  k_embed_mfma<<<4096, 256, 0, stream>>>(input_ids, tbl, wih,
                                         b_ih_f, b_hh_f, b_ih_b, b_hh_b, Pf, Pb);

  // 2) full recurrence: persistent kernel, barrier-lite (memory-side atomics)
  k_lstm_all<<<256, 64, 0, stream>>>(whh, (const unsigned short*)Pf,
                                     (const unsigned short*)Pb,
                                     c0, hInit, hHist, bar);

  // 3) emissions from bf16 h-history (MFMA)
  k_em_mfma<<<cM / 128, 256, 0, stream>>>((const unsigned short*)hHist, WoutP,
                                          b_out, em);

  // 4) CRF per batch element + final mean
  k_crf<<<cB, 320, 0, stream>>>(em, tag_ids, lengths, start_trans, end_trans, trans, llh);
  k_final<<<1, 256, 0, stream>>>(llh, out);
}